// Round 4
// baseline (397.231 us; speedup 1.0000x reference)
//
#include <hip/hip_runtime.h>
#include <math.h>

// NeRF ray-march forward (MipRayMarcher2), QUAD-per-ray.
// 4 threads own one ray: thread t holds samples 12t..12t+11 (contiguous ->
// fully coalesced loads). Local march per thread, spliced by a 3-shuffle
// exclusive product scan across the quad. ~1 cross-lane op per ray.
// nRays = 262144, 48 samples, 47 intervals.

#define S_SAMPLES 48
#define S_INTERVALS 47

__device__ __forceinline__ unsigned f2u_sortable(float f) {
    unsigned u = __float_as_uint(f);
    return (u & 0x80000000u) ? ~u : (u | 0x80000000u);
}
__device__ __forceinline__ float u2f_sortable(unsigned u) {
    return (u & 0x80000000u) ? __uint_as_float(u ^ 0x80000000u)
                             : __uint_as_float(~u);
}

__global__ void init_ws_kernel(unsigned* ws) {
    ws[0] = 0xFFFFFFFFu;  // min identity
    ws[1] = 0u;           // max identity
}

__global__ __launch_bounds__(256) void raymarch_kernel(
    const float* __restrict__ colors,     // [nRays, 48, 3]
    const float* __restrict__ densities,  // [nRays, 48]
    const float* __restrict__ depths,     // [nRays, 48]
    unsigned* __restrict__ ws,            // out: sortable-uint gmin/gmax
    float* __restrict__ out_rgb,          // [nRays, 3]
    float* __restrict__ out_depth,        // [nRays] (unclamped here)
    float* __restrict__ out_w,            // [nRays, 47]
    int nRays) {
    const int tid = blockIdx.x * 256 + threadIdx.x;
    const int ray = tid >> 2;          // 4 threads per ray
    const int t = threadIdx.x & 3;     // quad slot: samples 12t..12t+11
    const bool live = (ray < nRays);
    const int rayc = live ? ray : (nRays - 1);  // keep lanes active for shuffles

    // ---- coalesced loads: 3+3+9 float4, contiguous per thread ----
    const float4* dp = (const float4*)(depths + (size_t)rayc * S_SAMPLES) + 3 * t;
    const float4* np = (const float4*)(densities + (size_t)rayc * S_SAMPLES) + 3 * t;
    const float4* cp = (const float4*)(colors + (size_t)rayc * (S_SAMPLES * 3)) + 9 * t;

    float4 d0 = dp[0], d1 = dp[1], d2 = dp[2];
    float4 n0 = np[0], n1 = np[1], n2 = np[2];
    float4 c0 = cp[0], c1 = cp[1], c2 = cp[2], c3 = cp[3], c4 = cp[4];
    float4 c5 = cp[5], c6 = cp[6], c7 = cp[7], c8 = cp[8];

    float dep[12] = {d0.x, d0.y, d0.z, d0.w, d1.x, d1.y, d1.z, d1.w,
                     d2.x, d2.y, d2.z, d2.w};
    float den[12] = {n0.x, n0.y, n0.z, n0.w, n1.x, n1.y, n1.z, n1.w,
                     n2.x, n2.y, n2.z, n2.w};
    float col[36] = {c0.x, c0.y, c0.z, c0.w, c1.x, c1.y, c1.z, c1.w,
                     c2.x, c2.y, c2.z, c2.w, c3.x, c3.y, c3.z, c3.w,
                     c4.x, c4.y, c4.z, c4.w, c5.x, c5.y, c5.z, c5.w,
                     c6.x, c6.y, c6.z, c6.w, c7.x, c7.y, c7.z, c7.w,
                     c8.x, c8.y, c8.z, c8.w};

    // ---- boundary sample (first sample of thread t+1) via shuffle ----
    float bdDep = __shfl_down(d0.x, 1);
    float bdDen = __shfl_down(n0.x, 1);
    float bdC0 = __shfl_down(c0.x, 1);
    float bdC1 = __shfl_down(c0.y, 1);
    float bdC2 = __shfl_down(c0.z, 1);

    // ---- local march: 12 intervals (11 for t==3), local transmittance ----
    const float LOG2E = 1.4426950408889634f;
    float T = 1.f;
    float wv[12];
    float s0 = 0.f, s1 = 0.f, s2 = 0.f, sw = 0.f, sd = 0.f;
#pragma unroll
    for (int j = 0; j < 12; ++j) {
        const bool has = (t < 3) || (j < 11);
        float dB = (j < 11) ? dep[j + 1] : bdDep;
        float nB = (j < 11) ? den[j + 1] : bdDen;
        float cB0 = (j < 11) ? col[3 * j + 3] : bdC0;
        float cB1 = (j < 11) ? col[3 * j + 4] : bdC1;
        float cB2 = (j < 11) ? col[3 * j + 5] : bdC2;

        float delta = dB - dep[j];
        float xs = (0.5f * (den[j] + nB) - 1.f) * LOG2E;
        // log2(1 + e^x) = max(xs,0) + log2(1 + 2^-|xs|)
        float sp2 = fmaxf(xs, 0.f) + log2f(1.f + exp2f(-fabsf(xs)));
        float alpha = 1.f - exp2f(-delta * sp2);
        if (!has) alpha = 0.f;

        float w = alpha * T;
        T *= (1.f - alpha + 1e-10f);
        wv[j] = w;
        s0 = fmaf(w, 0.5f * (col[3 * j + 0] + cB0), s0);
        s1 = fmaf(w, 0.5f * (col[3 * j + 1] + cB1), s1);
        s2 = fmaf(w, 0.5f * (col[3 * j + 2] + cB2), s2);
        sw += w;
        sd = fmaf(w, 0.5f * (dep[j] + dB), sd);
    }

    // ---- exclusive product scan of local transmittance across the quad ----
    float P = T;
    float u1 = __shfl_up(P, 1);
    float q = (t >= 1) ? P * u1 : P;           // incl depth 2
    float u2 = __shfl_up(q, 2);
    float incl = (t >= 2) ? q * u2 : q;        // inclusive product
    float u3 = __shfl_up(incl, 1);
    float Texc = (t >= 1) ? u3 : 1.f;          // exclusive product

    // ---- scale + store weights (dense tiled scalar stores, L2-merged) ----
    if (live) {
        float* wp = out_w + (size_t)ray * S_INTERVALS + 12 * t;
#pragma unroll
        for (int j = 0; j < 12; ++j) {
            if ((t < 3) || (j < 11)) wp[j] = wv[j] * Texc;
        }
    }

    // ---- quad reduction of the 5 sums ----
    s0 *= Texc; s1 *= Texc; s2 *= Texc; sw *= Texc; sd *= Texc;
#pragma unroll
    for (int off = 1; off <= 2; off <<= 1) {
        s0 += __shfl_xor(s0, off);
        s1 += __shfl_xor(s1, off);
        s2 += __shfl_xor(s2, off);
        sw += __shfl_xor(sw, off);
        sd += __shfl_xor(sd, off);
    }

    if (t == 0 && live) {
        size_t rb = (size_t)ray * 3;
        out_rgb[rb + 0] = fmaf(s0, 2.f, -1.f);
        out_rgb[rb + 1] = fmaf(s1, 2.f, -1.f);
        out_rgb[rb + 2] = fmaf(s2, 2.f, -1.f);
        out_depth[ray] = sd / sw;  // NaN fixed in clamp pass
    }

    // ---- global depth min/max (depths sorted along samples) ----
    float mnd = (t == 0 && live) ? d0.x : INFINITY;    // sample 0
    float mxd = (t == 3 && live) ? d2.w : -INFINITY;   // sample 47
#pragma unroll
    for (int off = 32; off; off >>= 1) {
        mnd = fminf(mnd, __shfl_xor(mnd, off));
        mxd = fmaxf(mxd, __shfl_xor(mxd, off));
    }
    if ((threadIdx.x & 63) == 0) {
        atomicMin(&ws[0], f2u_sortable(mnd));
        atomicMax(&ws[1], f2u_sortable(mxd));
    }
}

__global__ __launch_bounds__(256) void clamp_depth_kernel(
    float* __restrict__ out_depth, const unsigned* __restrict__ ws, int n) {
    int i = blockIdx.x * blockDim.x + threadIdx.x;
    if (i < n) {
        float gmin = u2f_sortable(ws[0]);
        float gmax = u2f_sortable(ws[1]);
        float d = out_depth[i];
        if (isnan(d)) d = INFINITY;  // nan_to_num(nan=inf)
        d = fminf(fmaxf(d, gmin), gmax);
        out_depth[i] = d;
    }
}

extern "C" void kernel_launch(void* const* d_in, const int* in_sizes, int n_in,
                              void* d_out, int out_size, void* d_ws, size_t ws_size,
                              hipStream_t stream) {
    const float* colors = (const float*)d_in[0];
    const float* densities = (const float*)d_in[1];
    const float* depths = (const float*)d_in[2];

    const int nRays = in_sizes[2] / S_SAMPLES;  // 262144

    float* out = (float*)d_out;
    float* out_rgb = out;                        // nRays*3
    float* out_depth = out + (size_t)nRays * 3;  // nRays
    float* out_w = out + (size_t)nRays * 4;      // nRays*47

    unsigned* ws = (unsigned*)d_ws;

    init_ws_kernel<<<1, 1, 0, stream>>>(ws);

    const long long nThreads = (long long)nRays * 4;
    const int nBlocks = (int)((nThreads + 255) / 256);
    raymarch_kernel<<<nBlocks, 256, 0, stream>>>(
        colors, densities, depths, ws, out_rgb, out_depth, out_w, nRays);
    clamp_depth_kernel<<<(nRays + 255) / 256, 256, 0, stream>>>(out_depth, ws, nRays);
}